// Round 3
// baseline (279.840 us; speedup 1.0000x reference)
//
#include <hip/hip_runtime.h>
#include <hip/hip_bf16.h>

// Problem constants (SOnEquivalentLayer)
#define N_ATOMS 20000
#define N_EDGES 200000
#define CCH     64      // channels
#define KRBF    20      // radial features
#define RCUT    5.0f
#define INV_NORM 0.1f   // 1/norm_factor
#define PI_F    3.14159265358979323846f

// COMBOS = [(0,0,0),(0,1,1),(0,2,2),(1,0,1),(1,1,0),(1,1,2),(1,2,1),(2,0,2),(2,1,1),(2,2,0),(2,2,2)]
// Per-edge, per-channel contributions (fn[k] = rbf . rbf_w[k], scaled by 1/NORM):
//   out0        += fn0*s0 + fn4*(v.u) + fn9*(u.M.u)
//   out1[a]     += fn1*s0*u[a] + fn3*v[a] + fn6*(v.u)*u[a] + fn8*Mu[a]
//   out2[a][b]  += fn2*s0*u[a]*u[b] + fn5*v[a]*u[b] + fn7*M[a][b] + fn10*Mu[a]*u[b]
// where s0=t0[j,c], v=t1[j,c,:], M=t2[j,c,:,:], Mu[a]=sum_x M[a][x]u[x].

__device__ __forceinline__ float sigm(float x) { return 1.0f / (1.0f + __expf(-x)); }

__global__ __launch_bounds__(256) void edge_kernel(
    const float* __restrict__ t0,
    const float* __restrict__ t1,
    const float* __restrict__ t2,
    const float* __restrict__ coords,
    const int* __restrict__ edge_index,      // [2, E]
    const float* __restrict__ rbf_w,         // [11, K, C]
    float* __restrict__ agg0,                // [N, C]
    float* __restrict__ agg1,                // [N, C, 3]
    float* __restrict__ agg2)                // [N, C, 9]
{
    const int wave = (int)((blockIdx.x * blockDim.x + threadIdx.x) >> 6);
    const int lane = threadIdx.x & 63;       // lane = channel
    if (wave >= N_EDGES) return;

    const int ai = edge_index[wave];            // destination (idx_i)
    const int aj = edge_index[N_EDGES + wave];  // source      (idx_j)

    // rij = coord[j] - coord[i]  (wave-uniform; broadcast loads)
    const float rx = coords[aj * 3 + 0] - coords[ai * 3 + 0];
    const float ry = coords[aj * 3 + 1] - coords[ai * 3 + 1];
    const float rz = coords[aj * 3 + 2] - coords[ai * 3 + 2];
    const float d  = sqrtf(rx * rx + ry * ry + rz * rz + 1e-12f);

    // fc == 0 exactly for d >= RCUT (fp32 cos(pi) rounds to -1), so those
    // edges contribute nothing — ~98% early exit (uniform coords in a 30^3 box).
    if (d >= RCUT) return;

    const float inv_d = 1.0f / d;
    const float u0 = rx * inv_d, u1 = ry * inv_d, u2 = rz * inv_d;
    const float fc   = 0.5f * (cosf(PI_F * (d * (1.0f / RCUT))) + 1.0f);
    // sqrt(2/RC) * fc / d * (1/NORM) folded into every rbf value
    const float coef = 0.632455532033676f * fc * inv_d * INV_NORM;

    float rbf[KRBF];
    const float base = PI_F * d * (1.0f / RCUT);
#pragma unroll
    for (int kk = 0; kk < KRBF; kk++)
        rbf[kk] = coef * sinf((float)(kk + 1) * base);

    // fn[k][lane] = sum_kk rbf[kk] * rbf_w[k, kk, lane]   (L1/L2-hot, coalesced)
    float fn[11];
#pragma unroll
    for (int k = 0; k < 11; k++) {
        float s = 0.0f;
#pragma unroll
        for (int kk = 0; kk < KRBF; kk++)
            s += rbf[kk] * rbf_w[k * (KRBF * CCH) + kk * CCH + lane];
        fn[k] = s;
    }

    // Gather source features for this channel
    const int cj = aj * CCH + lane;
    const float s0 = t0[cj];
    float v[3];
#pragma unroll
    for (int a = 0; a < 3; a++) v[a] = t1[cj * 3 + a];
    float M[9];
#pragma unroll
    for (int e = 0; e < 9; e++) M[e] = t2[cj * 9 + e];

    const float u[3] = { u0, u1, u2 };
    const float dvu = v[0] * u0 + v[1] * u1 + v[2] * u2;
    float Mu[3];
#pragma unroll
    for (int a = 0; a < 3; a++)
        Mu[a] = M[a * 3 + 0] * u0 + M[a * 3 + 1] * u1 + M[a * 3 + 2] * u2;
    const float uMu = u0 * Mu[0] + u1 * Mu[1] + u2 * Mu[2];

    const int ci = ai * CCH + lane;
    atomicAdd(&agg0[ci], fn[0] * s0 + fn[4] * dvu + fn[9] * uMu);
#pragma unroll
    for (int a = 0; a < 3; a++)
        atomicAdd(&agg1[ci * 3 + a],
                  fn[1] * s0 * u[a] + fn[3] * v[a] + fn[6] * dvu * u[a] + fn[8] * Mu[a]);
#pragma unroll
    for (int a = 0; a < 3; a++) {
        const float t5  = fn[5] * v[a];
        const float t2s = fn[2] * s0 * u[a];
        const float t10 = fn[10] * Mu[a];
#pragma unroll
        for (int b = 0; b < 3; b++)
            atomicAdd(&agg2[ci * 9 + a * 3 + b],
                      t2s * u[b] + t5 * u[b] + fn[7] * M[a * 3 + b] + t10 * u[b]);
    }
}

__global__ __launch_bounds__(256) void atom_kernel(
    const float* __restrict__ t0,
    const float* __restrict__ t1,
    const float* __restrict__ t2,
    const float* __restrict__ agg0,
    const float* __restrict__ agg1,
    const float* __restrict__ agg2,
    const float* __restrict__ w0,
    const float* __restrict__ b0,
    const float* __restrict__ w1,
    const float* __restrict__ w2,
    const float* __restrict__ actw,          // [3, C]
    float* __restrict__ out0,                // [N, C]      (fp32 output!)
    float* __restrict__ out1,                // [N, C, 3]
    float* __restrict__ out2)                // [N, C, 3, 3]
{
    // 4 waves per block, 1 atom per wave. 20000 % 4 == 0 so every thread is live.
    __shared__ float L[4][13 * CCH];   // [0,64): agg0 | [64,256): agg1 | [256,832): agg2
    const int wib  = threadIdx.x >> 6;
    const int lane = threadIdx.x & 63;
    const int n    = blockIdx.x * 4 + wib;
    float* Lw = L[wib];

    // Stage agg = residual t + edge sums (fp32)
    {
        const int c = lane;
        Lw[c] = t0[n * CCH + c] + agg0[n * CCH + c];
#pragma unroll
        for (int a = 0; a < 3; a++)
            Lw[CCH + c * 3 + a] = t1[(n * CCH + c) * 3 + a] + agg1[(n * CCH + c) * 3 + a];
#pragma unroll
        for (int e = 0; e < 9; e++)
            Lw[4 * CCH + c * 9 + e] = t2[(n * CCH + c) * 9 + e] + agg2[(n * CCH + c) * 9 + e];
    }
    __syncthreads();

    const int o = lane;   // output channel
    float y0 = b0[o];
    float y1[3] = { 0.f, 0.f, 0.f };
    float y2[9] = { 0.f, 0.f, 0.f, 0.f, 0.f, 0.f, 0.f, 0.f, 0.f };
#pragma unroll 4
    for (int c = 0; c < CCH; c++) {
        const float wv0 = w0[c * CCH + o];   // coalesced across lanes
        const float wv1 = w1[c * CCH + o];
        const float wv2 = w2[c * CCH + o];
        y0 += Lw[c] * wv0;                   // LDS broadcast reads
#pragma unroll
        for (int a = 0; a < 3; a++) y1[a] += Lw[CCH + c * 3 + a] * wv1;
#pragma unroll
        for (int e = 0; e < 9; e++) y2[e] += Lw[4 * CCH + c * 9 + e] * wv2;
    }

    const float aw0 = actw[o];
    const float aw1 = actw[CCH + o];
    const float aw2 = actw[2 * CCH + o];

    // way-0: learnable swish, + residual agg0
    const float z0 = y0 * sigm(aw0 * y0);
    out0[n * CCH + o] = z0 + Lw[o];

    // way-1: norm-gated sigmoid
    const float nn1 = sqrtf(y1[0] * y1[0] + y1[1] * y1[1] + y1[2] * y1[2] + 1e-12f);
    const float g1 = sigm(aw1 * nn1);
#pragma unroll
    for (int a = 0; a < 3; a++)
        out1[(n * CCH + o) * 3 + a] = y1[a] * g1 + Lw[CCH + o * 3 + a];

    // way-2: norm-gated sigmoid over 3x3
    float s2 = 1e-12f;
#pragma unroll
    for (int e = 0; e < 9; e++) s2 += y2[e] * y2[e];
    const float g2 = sigm(aw2 * sqrtf(s2));
#pragma unroll
    for (int e = 0; e < 9; e++)
        out2[(n * CCH + o) * 9 + e] = y2[e] * g2 + Lw[4 * CCH + o * 9 + e];
}

extern "C" void kernel_launch(void* const* d_in, const int* in_sizes, int n_in,
                              void* d_out, int out_size, void* d_ws, size_t ws_size,
                              hipStream_t stream) {
    const float* t0     = (const float*)d_in[0];
    const float* t1     = (const float*)d_in[1];
    const float* t2     = (const float*)d_in[2];
    const float* coords = (const float*)d_in[3];
    const int*   eidx   = (const int*)d_in[4];
    const float* rbfw   = (const float*)d_in[5];
    const float* w0     = (const float*)d_in[6];
    const float* b0     = (const float*)d_in[7];
    const float* w1     = (const float*)d_in[8];
    const float* w2     = (const float*)d_in[9];
    const float* actw   = (const float*)d_in[10];

    // fp32 aggregate scratch: agg0 [N,C], agg1 [N,C,3], agg2 [N,C,9]
    float* agg0 = (float*)d_ws;
    float* agg1 = agg0 + (size_t)N_ATOMS * CCH;
    float* agg2 = agg1 + (size_t)N_ATOMS * CCH * 3;
    const size_t aggBytes = (size_t)N_ATOMS * CCH * 13 * sizeof(float);
    if (ws_size < aggBytes) return;  // scratch guard

    hipMemsetAsync(d_ws, 0, aggBytes, stream);

    float* o0 = (float*)d_out;
    float* o1 = o0 + (size_t)N_ATOMS * CCH;
    float* o2 = o1 + (size_t)N_ATOMS * CCH * 3;

    // 1 wave per edge (4 edges / 256-thread block)
    edge_kernel<<<(N_EDGES + 3) / 4, 256, 0, stream>>>(
        t0, t1, t2, coords, eidx, rbfw, agg0, agg1, agg2);

    // 1 wave per atom (4 atoms / block); 20000 / 4 = 5000 blocks exactly
    atom_kernel<<<N_ATOMS / 4, 256, 0, stream>>>(
        t0, t1, t2, agg0, agg1, agg2, w0, b0, w1, w2, actw, o0, o1, o2);
}